// Round 20
// baseline (243.928 us; speedup 1.0000x reference)
//
#include <hip/hip_runtime.h>
#include <hip/hip_bf16.h>

// SetMatchingModel S=48,N=80,D=128,H=2,HS=128.
// v20 = round-19 (best, 240us) with the front-end cleaned up:
//  - cvt_k pre-converts x,W1,W2,W3,Wq/Wk (enc+dec) to bf16 ONCE (the old
//    mgemm/qkv staging re-converted weights per block, 60x redundantly)
//  - bgemm_k: pure-bf16 staging both operands (no f2b in hot loop)
//  - nmgemm_k: MLP3 with fused row-norm epilogue -> hbp (permuted f32) +
//    z1 bf16; deletes norm_k launch + hb round-trip. enc residual reads
//    the permuted layout (same as dec).
// dec8_k / up_k unchanged from round 19.

#define SS 48
#define NI 80

typedef unsigned short us;
typedef __attribute__((ext_vector_type(8))) short s8v;   // 8 bf16
typedef __attribute__((ext_vector_type(4))) float f4v;   // 4 f32

#define MFMA(a,b,c) __builtin_amdgcn_mfma_f32_16x16x32_bf16((a),(b),(c),0,0,0)

__device__ __forceinline__ float gelu_f(float x){
  return 0.5f * x * (1.0f + erff(x * 0.7071067811865475f));
}
__device__ __forceinline__ us f2b(float f){
  __hip_bfloat16 b = __float2bfloat16(f);
  return reinterpret_cast<us&>(b);
}
__device__ __forceinline__ s8v zero8(){ s8v v = {0,0,0,0,0,0,0,0}; return v; }
__device__ __forceinline__ void gl16(const void* g, void* l){
  __builtin_amdgcn_global_load_lds(
      (const __attribute__((address_space(1))) void*)g,
      (__attribute__((address_space(3))) void*)l, 16, 0, 0);
}

// ---------------- cvt_k: bulk f32 -> bf16 conversions -----------------------
__global__ __launch_bounds__(256) void cvt_k(
    const float* __restrict__ x,    const float* __restrict__ W1,
    const float* __restrict__ W2,   const float* __restrict__ W3,
    const float* __restrict__ Wq_s, const float* __restrict__ Wk_s,
    const float* __restrict__ Wq_c, const float* __restrict__ Wk_c,
    us* __restrict__ xb,   us* __restrict__ W1b, us* __restrict__ W2b,
    us* __restrict__ W3b,  us* __restrict__ Wqsb, us* __restrict__ Wksb,
    us* __restrict__ Wqcb, us* __restrict__ Wkcb)
{
  const int NX = 1966080;
  const int C1 = NX + 262144, C2 = C1 + 131072, C3 = C2 + 32768;
  const int C4 = C3 + 32768, C5 = C4 + 32768, C6 = C5 + 32768, C7 = C6 + 32768;
  for (int idx = blockIdx.x*256 + threadIdx.x; idx < C7;
       idx += gridDim.x*256) {
    if (idx < NX)      xb[idx]        = f2b(x[idx]);
    else if (idx < C1) W1b[idx - NX]  = f2b(W1[idx - NX]);
    else if (idx < C2) W2b[idx - C1]  = f2b(W2[idx - C1]);
    else if (idx < C3) W3b[idx - C2]  = f2b(W3[idx - C2]);
    else if (idx < C4) Wqsb[idx - C3] = f2b(Wq_s[idx - C3]);
    else if (idx < C5) Wksb[idx - C4] = f2b(Wk_s[idx - C4]);
    else if (idx < C6) Wqcb[idx - C5] = f2b(Wq_c[idx - C5]);
    else               Wkcb[idx - C6] = f2b(Wk_c[idx - C6]);
  }
}

// ---------------- merged weight prep (WfcT, Wvh bf16, M) --------------------
__global__ __launch_bounds__(128) void prep_k(
    const float* __restrict__ Wh_s, const float* __restrict__ Wfc_e,
    const float* __restrict__ Wh_c, const float* __restrict__ Wfc_d,
    const float* __restrict__ Wcs,  const float* __restrict__ Wv_s,
    const float* __restrict__ Wv_c,
    us* __restrict__ WfcTe, us* __restrict__ WfcTd,
    us* __restrict__ Wvhb_s, us* __restrict__ Wvhb_c,
    us* __restrict__ Mb)
{
  const int x = blockIdx.x, task = blockIdx.y, tid = threadIdx.x;
  if (task == 0) {
    WfcTe[x*128 + tid] = f2b(Wfc_e[(size_t)tid*128 + x]);
  } else if (task == 1) {
    WfcTd[x*128 + tid] = f2b(Wfc_d[(size_t)tid*128 + x]);
  } else if (task < 6) {
    int h = (task - 2) & 1;
    const float* Wv = task < 4 ? Wv_s : Wv_c;
    const float* Wh = task < 4 ? Wh_s : Wh_c;
    us* Wvh = task < 4 ? Wvhb_s : Wvhb_c;
    float acc = 0.f;
#pragma unroll 8
    for (int d = 0; d < 128; ++d)
      acc = fmaf(Wv[(size_t)x*256 + h*128 + d], Wh[(size_t)(h*128 + d)*128 + tid], acc);
    Wvh[(size_t)x*256 + h*128 + tid] = f2b(acc);
  } else {
    int h = task - 6;
    float acc = 0.f;
#pragma unroll 8
    for (int k = 0; k < 128; ++k)
      acc = fmaf(Wcs[(size_t)x*256 + h*128 + k], Wcs[(size_t)tid*256 + h*128 + k], acc);
    Mb[(size_t)h*16384 + x*128 + tid] = f2b(acc);
  }
}

// ---------------- bgemm: all-bf16 GEMM, C = gelu(A@B), bf16 out -------------
__global__ __launch_bounds__(256) void bgemm_k(const us* __restrict__ A,
    const us* __restrict__ B, us* __restrict__ C, int N, int K)
{
  __shared__ __align__(16) char lds[10240];
  char* As = lds; char* Bs = lds + 5120;
  const int t = threadIdx.x;
  const int wv = t >> 6, lm = t & 15, lh = (t >> 4) & 3;
  const int bx = blockIdx.x, by = blockIdx.y;
  const int ar = wv*16 + lm, r0 = wv*16 + lh*4;
  f4v acc[4];
#pragma unroll
  for (int ct = 0; ct < 4; ++ct) acc[ct] = {0.f,0.f,0.f,0.f};
  const int rA = t >> 2, kcA = (t & 3) << 3;
  const int kkB = t >> 3, nnB = (t & 7) << 3;
  for (int k0 = 0; k0 < K; k0 += 32) {
    __syncthreads();
    {
      s8v v = *(const s8v*)(A + (size_t)(by*64 + rA)*K + k0 + kcA);
      *(s8v*)(As + rA*80 + kcA*2) = v;
      s8v wv8 = *(const s8v*)(B + (size_t)(k0 + kkB)*N + bx*64 + nnB);
      const us* wp = (const us*)&wv8;
#pragma unroll
      for (int q = 0; q < 8; ++q)
        *(us*)(Bs + (nnB + q)*80 + kkB*2) = wp[q];
    }
    __syncthreads();
    s8v af = *(const s8v*)(As + ar*80 + lh*16);
#pragma unroll
    for (int ct = 0; ct < 4; ++ct) {
      s8v bf = *(const s8v*)(Bs + (ct*16 + lm)*80 + lh*16);
      acc[ct] = MFMA(af, bf, acc[ct]);
    }
  }
#pragma unroll
  for (int ct = 0; ct < 4; ++ct)
#pragma unroll
    for (int reg = 0; reg < 4; ++reg)
      C[(size_t)(by*64 + r0 + reg)*N + bx*64 + ct*16 + lm] = f2b(gelu_f(acc[ct][reg]));
}

// ---------------- nmgemm: MLP3 (K=256, N=128) + fused row-norm --------------
// out: hbp (PERMUTED f32: hbp[row*128 + lm*8 + dt] = val(col dt*16+lm))
//      z1b (natural bf16 [row][128], normed)
__global__ __launch_bounds__(256) void nmgemm_k(const us* __restrict__ A,
    const us* __restrict__ B, float* __restrict__ hbp, us* __restrict__ z1b)
{
  __shared__ __align__(16) char lds[15360];  // As 64x80B=5120 + Bs 128x80B=10240
  char* As = lds; char* Bs = lds + 5120;
  const int t = threadIdx.x;
  const int wv = t >> 6, lm = t & 15, lh = (t >> 4) & 3;
  const int by = blockIdx.x;
  const int ar = wv*16 + lm, r0 = wv*16 + lh*4;
  f4v acc[8];
#pragma unroll
  for (int ct = 0; ct < 8; ++ct) acc[ct] = {0.f,0.f,0.f,0.f};
  const int rA = t >> 2, kcA = (t & 3) << 3;
  const int kkB = t >> 3, nnB = (t & 7) << 4;
#pragma unroll 1
  for (int k0 = 0; k0 < 256; k0 += 32) {
    __syncthreads();
    {
      s8v v = *(const s8v*)(A + (size_t)(by*64 + rA)*256 + k0 + kcA);
      *(s8v*)(As + rA*80 + kcA*2) = v;
#pragma unroll
      for (int q2 = 0; q2 < 2; ++q2) {
        s8v wv8 = *(const s8v*)(B + (size_t)(k0 + kkB)*128 + nnB + q2*8);
        const us* wp = (const us*)&wv8;
#pragma unroll
        for (int q = 0; q < 8; ++q)
          *(us*)(Bs + (nnB + q2*8 + q)*80 + kkB*2) = wp[q];
      }
    }
    __syncthreads();
    s8v af = *(const s8v*)(As + ar*80 + lh*16);
#pragma unroll
    for (int ct = 0; ct < 8; ++ct) {
      s8v bf = *(const s8v*)(Bs + (ct*16 + lm)*80 + lh*16);
      acc[ct] = MFMA(af, bf, acc[ct]);
    }
  }
  // epilogue: gelu, row-norm (dec-style shfl over 16 lanes), dual store
#pragma unroll
  for (int reg = 0; reg < 4; ++reg) {
    int row = by*64 + r0 + reg;
    size_t gb = (size_t)row << 7;
    float g[8]; float sm = 0.f;
#pragma unroll
    for (int dt = 0; dt < 8; ++dt) { g[dt] = gelu_f(acc[dt][reg]); sm += g[dt]; }
    *(float4*)(hbp + gb + lm*8)     = make_float4(g[0],g[1],g[2],g[3]);
    *(float4*)(hbp + gb + lm*8 + 4) = make_float4(g[4],g[5],g[6],g[7]);
#pragma unroll
    for (int off = 1; off < 16; off <<= 1) sm += __shfl_xor(sm, off, 64);
    float mean = sm * (1.0f/128.0f);
    float vs = 0.f;
#pragma unroll
    for (int dt = 0; dt < 8; ++dt) { float d = g[dt] - mean; vs = fmaf(d, d, vs); }
#pragma unroll
    for (int off = 1; off < 16; off <<= 1) vs += __shfl_xor(vs, off, 64);
    float inv = 1.f / (sqrtf(vs * (1.0f/128.0f)) + 1e-3f);
    bool keep = (sm != 0.f);
#pragma unroll
    for (int dt = 0; dt < 8; ++dt)
      z1b[gb + dt*16 + lm] = f2b(keep ? (g[dt]-mean)*inv : 0.f);
  }
}

// ---------------- qkv2: fused QKV GEMM, all-bf16 B, V -> VT scatter ---------
__global__ __launch_bounds__(256) void qkv2_k(const us* __restrict__ A,
    const us* __restrict__ Wq, const us* __restrict__ Wk,
    const us* __restrict__ Wv, us* __restrict__ Qb, us* __restrict__ Kb,
    us* __restrict__ VT)
{
  __shared__ __align__(16) char lds[10240];
  char* As = lds; char* Bs = lds + 5120;
  const int t = threadIdx.x;
  const int wv = t >> 6, lm = t & 15, lh = (t >> 4) & 3;
  const int bx = blockIdx.x, by = blockIdx.y;
  const int sel = bx >> 2, bxx = bx & 3;
  const us* B = sel == 0 ? Wq : (sel == 1 ? Wk : Wv);
  const int ar = wv*16 + lm, r0 = wv*16 + lh*4;
  f4v acc[4];
#pragma unroll
  for (int ct = 0; ct < 4; ++ct) acc[ct] = {0.f,0.f,0.f,0.f};
  const int rA = t >> 2, kcA = (t & 3) << 3;
  const int kkB = t >> 3, nnB = (t & 7) << 3;
#pragma unroll
  for (int k0 = 0; k0 < 128; k0 += 32) {
    __syncthreads();
    {
      s8v v = *(const s8v*)(A + (size_t)(by*64 + rA)*128 + k0 + kcA);
      *(s8v*)(As + rA*80 + kcA*2) = v;
      s8v wv8 = *(const s8v*)(B + (size_t)(k0 + kkB)*256 + bxx*64 + nnB);
      const us* wp = (const us*)&wv8;
#pragma unroll
      for (int q = 0; q < 8; ++q)
        *(us*)(Bs + (nnB + q)*80 + kkB*2) = wp[q];
    }
    __syncthreads();
    s8v af = *(const s8v*)(As + ar*80 + lh*16);
#pragma unroll
    for (int ct = 0; ct < 4; ++ct) {
      s8v bf = *(const s8v*)(Bs + (ct*16 + lm)*80 + lh*16);
      acc[ct] = MFMA(af, bf, acc[ct]);
    }
  }
  if (sel < 2) {
    us* O = sel ? Kb : Qb;
#pragma unroll
    for (int ct = 0; ct < 4; ++ct)
#pragma unroll
      for (int reg = 0; reg < 4; ++reg)
        O[(size_t)(by*64 + r0 + reg)*256 + bxx*64 + ct*16 + lm] = f2b(acc[ct][reg]);
  } else {
#pragma unroll
    for (int ct = 0; ct < 4; ++ct)
#pragma unroll
      for (int reg = 0; reg < 4; ++reg) {
        int r = by*64 + r0 + reg;
        int s = r / 80, m = r % 80;
        int d = bxx*64 + ct*16 + lm;
        VT[((size_t)s*256 + d)*80 + m] = f2b(acc[ct][reg]);
      }
  }
}

// ---------------- staged attention (drain-style; enc_k only, 48 blocks) -----
// baseg is PERMUTED f32 (hbp layout).
__device__ __forceinline__ void attn4e(int a, int t,
    const us* __restrict__ Qg, const us* __restrict__ Kg,
    const us* __restrict__ VTg, const float* __restrict__ baseg,
    const us* __restrict__ WfcT,
    char* __restrict__ X, char* __restrict__ Y, f4v x4[8])
{
  const int wv = t >> 6, lane = t & 63, lm = t & 15, lh = (t >> 4) & 3;
  const int ar = wv*16 + lm, r0 = wv*16 + lh*4;
  const float isq = 0.08838834764831845f;
  const int b = a;
#pragma unroll
  for (int dt = 0; dt < 8; ++dt) x4[dt] = (f4v){0.f,0.f,0.f,0.f};

#pragma unroll 1
  for (int h = 0; h < 2; ++h) {
    if (h == 1) __syncthreads();
#pragma unroll
    for (int c = 0; c < 4; ++c) {
      int chunk = wv*4 + c;
      int row = chunk*4 + (lane >> 4);
      int scb = ((lane & 15) << 4) ^ ((row & 7) << 4);
      gl16(Kg + (((size_t)(b*NI + row)) << 8) + h*128 + (scb >> 1), X + chunk*1024);
    }
    s8v qf[4];
    {
      const us* qrow = Qg + (((size_t)(a*NI + ar)) << 8) + h*128 + lh*8;
#pragma unroll
      for (int ks = 0; ks < 4; ++ks) qf[ks] = *(const s8v*)(qrow + ks*32);
    }
    __syncthreads();
    f4v sA[5];
#pragma unroll
    for (int nt = 0; nt < 5; ++nt) {
      int row = nt*16 + lm;
      f4v acc = (f4v){0.f,0.f,0.f,0.f};
#pragma unroll
      for (int ks = 0; ks < 4; ++ks) {
        s8v kf = *(const s8v*)(X + row*256 + ((ks*64 + lh*16) ^ ((row & 7) << 4)));
        acc = MFMA(qf[ks], kf, acc);
      }
      sA[nt] = acc;
    }
#pragma unroll
    for (int reg = 0; reg < 4; ++reg) {
      int r = r0 + reg;
      float sv[5];
#pragma unroll
      for (int nt = 0; nt < 5; ++nt) sv[nt] = sA[nt][reg] * isq;
      float mx = sv[0];
#pragma unroll
      for (int nt = 1; nt < 5; ++nt) mx = fmaxf(mx, sv[nt]);
#pragma unroll
      for (int off = 1; off < 16; off <<= 1) mx = fmaxf(mx, __shfl_xor(mx, off, 64));
      float e[5], sum = 0.f;
#pragma unroll
      for (int nt = 0; nt < 5; ++nt) {
        e[nt] = (sv[nt] != 0.f) ? __expf(sv[nt] - mx) : 0.f;
        sum += e[nt];
      }
#pragma unroll
      for (int off = 1; off < 16; off <<= 1) sum += __shfl_xor(sum, off, 64);
      float inv = 1.f / (sum + 1e-10f);
#pragma unroll
      for (int nt = 0; nt < 5; ++nt)
        *(us*)(Y + r*256 + ((2*(nt*16 + lm)) ^ ((r & 7) << 4))) = f2b(e[nt] * inv);
    }
    s8v pf0 = *(const s8v*)(Y + ar*256 + ((lh*16) ^ ((ar & 7) << 4)));
    s8v pf1 = *(const s8v*)(Y + ar*256 + ((64 + lh*16) ^ ((ar & 7) << 4)));
    s8v pf2 = zero8();
    if (lh < 2)
      pf2 = *(const s8v*)(Y + ar*256 + ((128 + lh*16) ^ ((ar & 7) << 4)));
    __syncthreads();
#pragma unroll
    for (int c = 0; c < 4; ++c) {
      int chunk = wv*4 + c;
      int L = chunk*1024 + lane*16;
      int rv = L / 160;
      int rem = L - rv*160;
      int cv = (rem >> 4) - (rv % 10); if (cv < 0) cv += 10;
      gl16(VTg + ((size_t)(b*256 + h*128 + rv))*80 + (cv << 3), X + chunk*1024);
    }
    __syncthreads();
#pragma unroll
    for (int dt = 0; dt < 8; ++dt) {
      int row = dt*16 + lm;
      int rm = (row % 10) << 4;
      int o0 = lh*16 + rm; if (o0 >= 160) o0 -= 160;
      x4[dt] = MFMA(pf0, *(const s8v*)(X + row*160 + o0), x4[dt]);
      int o1 = 64 + lh*16 + rm; if (o1 >= 160) o1 -= 160;
      x4[dt] = MFMA(pf1, *(const s8v*)(X + row*160 + o1), x4[dt]);
      s8v v2 = zero8();
      if (lh < 2) {
        int o2 = 128 + lh*16 + rm; if (o2 >= 160) o2 -= 160;
        v2 = *(const s8v*)(X + row*160 + o2);
      }
      x4[dt] = MFMA(pf2, v2, x4[dt]);
    }
    if (h == 1) {
#pragma unroll
      for (int reg = 0; reg < 4; ++reg) {
        const f4v* bp = (const f4v*)(baseg + (((size_t)(a*NI + r0 + reg)) << 7) + lm*8);
        f4v b0 = bp[0], b1 = bp[1];
#pragma unroll
        for (int dt = 0; dt < 4; ++dt) {
          x4[dt][reg]   += b0[dt];
          x4[dt+4][reg] += b1[dt];
        }
      }
    }
  }

  __syncthreads();
  for (int chunk = wv; chunk < 16; chunk += 5) {
    int row = chunk*4 + (lane >> 4);
    int scb = ((lane & 15) << 4) ^ ((row & 7) << 4);
    gl16(WfcT + (size_t)row*128 + (scb >> 1), X + chunk*1024);
  }
#pragma unroll
  for (int reg = 0; reg < 4; ++reg) {
    int r = r0 + reg;
    float sm = 0.f;
#pragma unroll
    for (int dt = 0; dt < 8; ++dt) sm += x4[dt][reg];
#pragma unroll
    for (int off = 1; off < 16; off <<= 1) sm += __shfl_xor(sm, off, 64);
    float mean = sm * (1.0f/128.0f);
    float vs = 0.f;
#pragma unroll
    for (int dt = 0; dt < 8; ++dt) { float d = x4[dt][reg] - mean; vs = fmaf(d, d, vs); }
#pragma unroll
    for (int off = 1; off < 16; off <<= 1) vs += __shfl_xor(vs, off, 64);
    float inv = 1.f / (sqrtf(vs * (1.0f/128.0f)) + 1e-3f);
    bool keep = (sm != 0.f);
#pragma unroll
    for (int dt = 0; dt < 8; ++dt)
      *(us*)(Y + r*256 + ((2*(dt*16 + lm)) ^ ((r & 7) << 4))) = f2b(keep ? (x4[dt][reg]-mean)*inv : 0.f);
  }
  s8v zf[4];
#pragma unroll
  for (int ks = 0; ks < 4; ++ks)
    zf[ks] = *(const s8v*)(Y + ar*256 + ((ks*64 + lh*16) ^ ((ar & 7) << 4)));
  __syncthreads();
#pragma unroll
  for (int dt = 0; dt < 4; ++dt) {
    int row = dt*16 + lm;
    f4v acc = (f4v){0.f,0.f,0.f,0.f};
#pragma unroll
    for (int ks = 0; ks < 4; ++ks) {
      s8v wfr = *(const s8v*)(X + row*256 + ((ks*64 + lh*16) ^ ((row & 7) << 4)));
      acc = MFMA(zf[ks], wfr, acc);
    }
#pragma unroll
    for (int reg = 0; reg < 4; ++reg) x4[dt][reg] += gelu_f(acc[reg]);
  }
  __syncthreads();
  for (int chunk = wv; chunk < 16; chunk += 5) {
    int row = chunk*4 + (lane >> 4);
    int scb = ((lane & 15) << 4) ^ ((row & 7) << 4);
    gl16(WfcT + (size_t)(row + 64)*128 + (scb >> 1), X + chunk*1024);
  }
  __syncthreads();
#pragma unroll
  for (int dt = 4; dt < 8; ++dt) {
    int row = dt*16 + lm;
    int r2 = row - 64;
    f4v acc = (f4v){0.f,0.f,0.f,0.f};
#pragma unroll
    for (int ks = 0; ks < 4; ++ks) {
      s8v wfr = *(const s8v*)(X + r2*256 + ((ks*64 + lh*16) ^ ((row & 7) << 4)));
      acc = MFMA(zf[ks], wfr, acc);
    }
#pragma unroll
    for (int reg = 0; reg < 4; ++reg) x4[dt][reg] += gelu_f(acc[reg]);
  }
}

// ---------------- encoder kernel --------------------------------------------
__global__ __launch_bounds__(320) void enc_k(
    const us* __restrict__ Qg, const us* __restrict__ Kg,
    const us* __restrict__ VTg, const float* __restrict__ hbp,
    const us* __restrict__ WfcT, float* __restrict__ e2p,
    us* __restrict__ z3b)
{
  __shared__ __align__(16) char X[20480];
  __shared__ __align__(16) char Y[20480];
  const int t = threadIdx.x;
  const int wv = t >> 6, lm = t & 15, lh = (t >> 4) & 3;
  const int r0 = wv*16 + lh*4;
  const int i = blockIdx.x;
  f4v x4[8];
  attn4e(i, t, Qg, Kg, VTg, hbp, WfcT, X, Y, x4);
#pragma unroll
  for (int reg = 0; reg < 4; ++reg) {
    int r = r0 + reg;
    size_t gb = ((size_t)(i*NI + r)) << 7;
    float tmp[8]; float sm = 0.f;
#pragma unroll
    for (int dt = 0; dt < 8; ++dt) { tmp[dt] = x4[dt][reg]; sm += tmp[dt]; }
    *(float4*)(e2p + gb + lm*8)     = make_float4(tmp[0],tmp[1],tmp[2],tmp[3]);
    *(float4*)(e2p + gb + lm*8 + 4) = make_float4(tmp[4],tmp[5],tmp[6],tmp[7]);
#pragma unroll
    for (int off = 1; off < 16; off <<= 1) sm += __shfl_xor(sm, off, 64);
    float mean = sm * (1.0f/128.0f);
    float vs = 0.f;
#pragma unroll
    for (int dt = 0; dt < 8; ++dt) { float d = tmp[dt] - mean; vs = fmaf(d, d, vs); }
#pragma unroll
    for (int off = 1; off < 16; off <<= 1) vs += __shfl_xor(vs, off, 64);
    float inv = 1.f / (sqrtf(vs * (1.0f/128.0f)) + 1e-3f);
    bool keep = (sm != 0.f);
#pragma unroll
    for (int dt = 0; dt < 8; ++dt)
      z3b[gb + dt*16 + lm] = f2b(keep ? (tmp[dt]-mean)*inv : 0.f);
  }
}

// ---------------- dec8_k: 640 thr, 2 groups, resident Wfc, 4 phases ---------
__global__ __launch_bounds__(640, 2) void dec8_k(
    const us* __restrict__ Qg, const us* __restrict__ Kg,
    const us* __restrict__ VTg, const float* __restrict__ e2p,
    const us* __restrict__ WfcT, us* __restrict__ x4g)
{
  __shared__ __align__(16) char L[155648];
  const int t = threadIdx.x;
  const int g = (t >= 320) ? 1 : 0;
  const int tg = t - g*320;
  const int wv = tg >> 6, wb = t >> 6;
  const int lane = t & 63, lm = t & 15, lh = (t >> 4) & 3;
  const int ar = wv*16 + lm, r0 = wv*16 + lh*4;
  const float isq = 0.08838834764831845f;
  const int a = blockIdx.x, b = blockIdx.y*2 + g;
  char* W  = L;
  char* S0 = L + 32768 + g*61440;
  char* S1 = S0 + 20480;
  char* Y  = S0 + 40960;

#define STG_K(DST, H)                                                        \
  { _Pragma("unroll") for (int c_ = 0; c_ < 4; ++c_) {                       \
      int ch_ = wv*4 + c_;                                                   \
      int rw_ = ch_*4 + (lane >> 4);                                         \
      int sc_ = ((lane & 15) << 4) ^ ((rw_ & 7) << 4);                       \
      gl16(Kg + (((size_t)(b*NI + rw_)) << 8) + (H)*128 + (sc_ >> 1),        \
           (DST) + ch_*1024); } }
#define STG_VT(DST, H)                                                       \
  { _Pragma("unroll") for (int c_ = 0; c_ < 4; ++c_) {                       \
      int ch_ = wv*4 + c_;                                                   \
      int L_ = ch_*1024 + lane*16;                                           \
      int rv_ = L_ / 160;                                                    \
      int cv_ = ((L_ - rv_*160) >> 4) - (rv_ % 10); if (cv_ < 0) cv_ += 10;  \
      gl16(VTg + ((size_t)(b*256 + (H)*128 + rv_))*80 + (cv_ << 3),          \
           (DST) + ch_*1024); } }
#define QKSM(KS, H)                                                          \
  { s8v qf_[4];                                                              \
    { const us* qr_ = Qg + (((size_t)(a*NI + ar)) << 8) + (H)*128 + lh*8;    \
      _Pragma("unroll") for (int ks = 0; ks < 4; ++ks)                       \
        qf_[ks] = *(const s8v*)(qr_ + ks*32); }                              \
    f4v sA_[5];                                                              \
    _Pragma("unroll") for (int nt = 0; nt < 5; ++nt) {                       \
      int rw_ = nt*16 + lm;                                                  \
      f4v ac_ = (f4v){0.f,0.f,0.f,0.f};                                      \
      _Pragma("unroll") for (int ks = 0; ks < 4; ++ks) {                     \
        s8v kf_ = *(const s8v*)((KS) + rw_*256 +                             \
                                ((ks*64 + lh*16) ^ ((rw_ & 7) << 4)));       \
        ac_ = MFMA(qf_[ks], kf_, ac_); }                                     \
      sA_[nt] = ac_; }                                                       \
    _Pragma("unroll") for (int reg = 0; reg < 4; ++reg) {                    \
      int r_ = r0 + reg;                                                     \
      float sv_[5];                                                          \
      _Pragma("unroll") for (int nt = 0; nt < 5; ++nt)                       \
        sv_[nt] = sA_[nt][reg] * isq;                                        \
      float mx_ = sv_[0];                                                    \
      _Pragma("unroll") for (int nt = 1; nt < 5; ++nt)                       \
        mx_ = fmaxf(mx_, sv_[nt]);                                           \
      _Pragma("unroll") for (int of_ = 1; of_ < 16; of_ <<= 1)               \
        mx_ = fmaxf(mx_, __shfl_xor(mx_, of_, 64));                          \
      float e_[5], su_ = 0.f;                                                \
      _Pragma("unroll") for (int nt = 0; nt < 5; ++nt) {                     \
        e_[nt] = (sv_[nt] != 0.f) ? __expf(sv_[nt] - mx_) : 0.f;             \
        su_ += e_[nt]; }                                                     \
      _Pragma("unroll") for (int of_ = 1; of_ < 16; of_ <<= 1)               \
        su_ += __shfl_xor(su_, of_, 64);                                     \
      float iv_ = 1.f / (su_ + 1e-10f);                                      \
      _Pragma("unroll") for (int nt = 0; nt < 5; ++nt)                       \
        *(us*)(Y + r_*256 + ((2*(nt*16 + lm)) ^ ((r_ & 7) << 4))) =          \
            f2b(e_[nt] * iv_); } }
#define PV(VS)                                                               \
  { s8v pf0_ = *(const s8v*)(Y + ar*256 + ((lh*16) ^ ((ar & 7) << 4)));      \
    s8v pf1_ = *(const s8v*)(Y + ar*256 + ((64 + lh*16) ^ ((ar & 7) << 4))); \
    s8v pf2_ = zero8();                                                      \
    if (lh < 2)                                                              \
      pf2_ = *(const s8v*)(Y + ar*256 + ((128 + lh*16) ^ ((ar & 7) << 4)));  \
    _Pragma("unroll") for (int dt = 0; dt < 8; ++dt) {                       \
      int rw_ = dt*16 + lm;                                                  \
      int rm_ = (rw_ % 10) << 4;                                             \
      int o0_ = lh*16 + rm_; if (o0_ >= 160) o0_ -= 160;                     \
      x4[dt] = MFMA(pf0_, *(const s8v*)((VS) + rw_*160 + o0_), x4[dt]);      \
      int o1_ = 64 + lh*16 + rm_; if (o1_ >= 160) o1_ -= 160;                \
      x4[dt] = MFMA(pf1_, *(const s8v*)((VS) + rw_*160 + o1_), x4[dt]);      \
      s8v v2_ = zero8();                                                     \
      if (lh < 2) { int o2_ = 128 + lh*16 + rm_;                             \
        if (o2_ >= 160) o2_ -= 160;                                          \
        v2_ = *(const s8v*)((VS) + rw_*160 + o2_); }                         \
      x4[dt] = MFMA(pf2_, v2_, x4[dt]); } }

  f4v x4[8];
#pragma unroll
  for (int dt = 0; dt < 8; ++dt) x4[dt] = (f4v){0.f,0.f,0.f,0.f};

  // prologue: resident Wfc (block-cooperative) + K0
  for (int ch = wb; ch < 32; ch += 10) {
    int row = ch*4 + (lane >> 4);
    int scb = ((lane & 15) << 4) ^ ((row & 7) << 4);
    gl16(WfcT + (size_t)row*128 + (scb >> 1), W + ch*1024);
  }
  STG_K(S0, 0);
  __syncthreads();
  // P0: issue VT0 -> S1; compute QK0 + softmax
  STG_VT(S1, 0);
  QKSM(S0, 0);
  __syncthreads();
  // P1: issue K1 -> S0; compute PV0
  STG_K(S0, 1);
  PV(S1);
  __syncthreads();
  // P2: issue VT1 -> S1; compute QK1 + softmax
  STG_VT(S1, 1);
  QKSM(S0, 1);
  __syncthreads();
  // P3 (final): PV1 + residual + norm + FC (all 8, resident W) + store
  PV(S1);
#pragma unroll
  for (int reg = 0; reg < 4; ++reg) {
    const f4v* bp = (const f4v*)(e2p + (((size_t)(a*NI + r0 + reg)) << 7) + lm*8);
    f4v bb0 = bp[0], bb1 = bp[1];
#pragma unroll
    for (int dt = 0; dt < 4; ++dt) {
      x4[dt][reg]   += bb0[dt];
      x4[dt+4][reg] += bb1[dt];
    }
  }
#pragma unroll
  for (int reg = 0; reg < 4; ++reg) {
    int r = r0 + reg;
    float sm = 0.f;
#pragma unroll
    for (int dt = 0; dt < 8; ++dt) sm += x4[dt][reg];
#pragma unroll
    for (int off = 1; off < 16; off <<= 1) sm += __shfl_xor(sm, off, 64);
    float mean = sm * (1.0f/128.0f);
    float vs = 0.f;
#pragma unroll
    for (int dt = 0; dt < 8; ++dt) { float d = x4[dt][reg] - mean; vs = fmaf(d, d, vs); }
#pragma unroll
    for (int off = 1; off < 16; off <<= 1) vs += __shfl_xor(vs, off, 64);
    float inv = 1.f / (sqrtf(vs * (1.0f/128.0f)) + 1e-3f);
    bool keep = (sm != 0.f);
#pragma unroll
    for (int dt = 0; dt < 8; ++dt)
      *(us*)(Y + r*256 + ((2*(dt*16 + lm)) ^ ((r & 7) << 4))) = f2b(keep ? (x4[dt][reg]-mean)*inv : 0.f);
  }
  {
    s8v zf[4];
#pragma unroll
    for (int ks = 0; ks < 4; ++ks)
      zf[ks] = *(const s8v*)(Y + ar*256 + ((ks*64 + lh*16) ^ ((ar & 7) << 4)));
#pragma unroll
    for (int dt = 0; dt < 8; ++dt) {
      int row = dt*16 + lm;
      f4v ac = (f4v){0.f,0.f,0.f,0.f};
#pragma unroll
      for (int ks = 0; ks < 4; ++ks) {
        s8v wf = *(const s8v*)(W + row*256 + ((ks*64 + lh*16) ^ ((row & 7) << 4)));
        ac = MFMA(zf[ks], wf, ac);
      }
#pragma unroll
      for (int reg = 0; reg < 4; ++reg) x4[dt][reg] += gelu_f(ac[reg]);
    }
  }
#pragma unroll
  for (int reg = 0; reg < 4; ++reg) {
    int r = r0 + reg;
#pragma unroll
    for (int dt = 0; dt < 8; ++dt)
      *(us*)(Y + r*256 + ((2*(dt*16 + lm)) ^ ((r & 7) << 4))) = f2b(x4[dt][reg]);
  }
  {
    char* dst = (char*)(x4g + ((size_t)a*SS + b)*10240);
#pragma unroll
    for (int q = 0; q < 4; ++q) {
      int c = lane + q*64;
      int row = wv*16 + (c >> 4);
      int cb = (c & 15) << 4;
      s8v v = *(const s8v*)(Y + row*256 + (cb ^ ((row & 7) << 4)));
      *(s8v*)(dst + row*256 + cb) = v;
    }
  }
#undef STG_K
#undef STG_VT
#undef QKSM
#undef PV
}

// ---------------- up_k: fused U-projection + score per unordered pair -------
__global__ __launch_bounds__(320) void up_k(
    const us* __restrict__ x4g, const us* __restrict__ Mb,
    const float* __restrict__ Wcs2, const float* __restrict__ xsg,
    float* __restrict__ outg)
{
  __shared__ __align__(16) char As[20480];
  __shared__ __align__(16) char Bs[16384];
  __shared__ __align__(16) char Xi[20480];
  __shared__ __align__(16) char Xu[40960];
  __shared__ float red[10];
  const int t = threadIdx.x;
  const int wv = t >> 6, lane = t & 63, lm = t & 15, lh = (t >> 4) & 3;
  const int ar = wv*16 + lm, r0 = wv*16 + lh*4;
  const float isq = 0.08838834764831845f;

  int bid0 = blockIdx.x;
  int bid = (bid0 & 7) * 147 + (bid0 >> 3);
  int ii = (int)(0.5f*(97.0f - sqrtf(9409.0f - 8.0f*(float)bid)));
  if (ii > 47) ii = 47; if (ii < 0) ii = 0;
  while (ii*SS - ii*(ii-1)/2 > bid) --ii;
  while ((ii+1)*SS - (ii+1)*ii/2 <= bid) ++ii;
  const int i = ii, j = ii + (bid - (ii*SS - ii*(ii-1)/2));
  const us* Aji = x4g + ((size_t)j*SS + i)*10240;
  const us* Aij = x4g + ((size_t)i*SS + j)*10240;

#pragma unroll
  for (int c = 0; c < 4; ++c) {
    int chunk = wv*4 + c;
    int row = chunk*4 + (lane >> 4);
    int scb = ((lane & 15) << 4) ^ ((row & 7) << 4);
    gl16(Aji + (size_t)row*128 + (scb >> 1), As + chunk*1024);
    gl16(Aij + (size_t)row*128 + (scb >> 1), Xi + chunk*1024);
  }
  f4v acc[16];
#pragma unroll
  for (int ct = 0; ct < 16; ++ct) acc[ct] = (f4v){0.f,0.f,0.f,0.f};
#pragma unroll 1
  for (int k0 = 0; k0 < 128; k0 += 32) {
    if (k0) __syncthreads();
    for (int c = wv; c < 16; c += 5) {
      int row = c*16 + (lane >> 2);
      int colb = (lane & 3) << 4;
      int scb = colb ^ ((row & 3) << 4);
      gl16(Mb + (size_t)row*128 + k0 + (scb >> 1), Bs + c*1024);
    }
    __syncthreads();
    int ks = k0 >> 5;
    s8v af = *(const s8v*)(As + ar*256 + ((ks*64 + lh*16) ^ ((ar & 7) << 4)));
#pragma unroll
    for (int ct = 0; ct < 16; ++ct) {
      int row = ct*16 + lm;
      s8v bf = *(const s8v*)(Bs + row*64 + ((lh*16) ^ ((row & 3) << 4)));
      acc[ct] = MFMA(af, bf, acc[ct]);
    }
  }
#pragma unroll
  for (int ct = 0; ct < 16; ++ct) {
    int h = ct >> 3;
    int cl = (ct & 7)*16 + lm;
#pragma unroll
    for (int reg = 0; reg < 4; ++reg) {
      int row = r0 + reg;
      *(us*)(Xu + h*20480 + row*256 + ((2*cl) ^ ((row & 7) << 4))) = f2b(acc[ct][reg]);
    }
  }
  __syncthreads();
  s8v xf[4];
#pragma unroll
  for (int ks = 0; ks < 4; ++ks)
    xf[ks] = *(const s8v*)(Xi + ar*256 + ((ks*64 + lh*16) ^ ((ar & 7) << 4)));
  float sc[2];
#pragma unroll 1
  for (int h = 0; h < 2; ++h) {
    const char* Xh = Xu + h*20480;
    float loc = 0.f;
#pragma unroll
    for (int nt = 0; nt < 5; ++nt) {
      int brow = nt*16 + lm;
      f4v ac = (f4v){0.f,0.f,0.f,0.f};
#pragma unroll
      for (int ks = 0; ks < 4; ++ks) {
        s8v bf = *(const s8v*)(Xh + brow*256 + ((ks*64 + lh*16) ^ ((brow & 7) << 4)));
        ac = MFMA(xf[ks], bf, ac);
      }
#pragma unroll
      for (int reg = 0; reg < 4; ++reg) loc += fmaxf(ac[reg]*isq, 0.f);
    }
    sc[h] = loc;
  }
#pragma unroll
  for (int off = 1; off < 64; off <<= 1) {
    sc[0] += __shfl_xor(sc[0], off, 64);
    sc[1] += __shfl_xor(sc[1], off, 64);
  }
  if ((t & 63) == 0) { red[wv] = sc[0]; red[wv + 5] = sc[1]; }
  __syncthreads();
  if (t == 0) {
    float s0 = red[0]+red[1]+red[2]+red[3]+red[4];
    float s1 = red[5]+red[6]+red[7]+red[8]+red[9];
    float val = (s0*Wcs2[0] + s1*Wcs2[1]) / (xsg[i]*xsg[j]);
    outg[i*SS + j] = val;
    outg[j*SS + i] = val;
  }
}

extern "C" void kernel_launch(void* const* d_in, const int* in_sizes, int n_in,
                              void* d_out, int out_size, void* d_ws, size_t ws_size,
                              hipStream_t stream)
{
  (void)in_sizes; (void)n_in; (void)out_size; (void)ws_size;
  const float* x     = (const float*)d_in[0];
  const float* xs    = (const float*)d_in[1];
  const float* W1    = (const float*)d_in[2];
  const float* W2    = (const float*)d_in[3];
  const float* W3    = (const float*)d_in[4];
  const float* Wq_s  = (const float*)d_in[5];
  const float* Wk_s  = (const float*)d_in[6];
  const float* Wv_s  = (const float*)d_in[7];
  const float* Wh_s  = (const float*)d_in[8];
  const float* Wfc_e = (const float*)d_in[9];
  const float* Wq_c  = (const float*)d_in[10];
  const float* Wk_c  = (const float*)d_in[11];
  const float* Wv_c  = (const float*)d_in[12];
  const float* Wh_c  = (const float*)d_in[13];
  const float* Wfc_d = (const float*)d_in[14];
  const float* Wcs   = (const float*)d_in[15];
  const float* Wcs2  = (const float*)d_in[16];
  float* out = (float*)d_out;

  char* w = (char*)d_ws;
  us* xb      = (us*)w;    w += (size_t)3840*512*2;
  us* W1b     = (us*)w;    w += (size_t)512*512*2;
  us* W2b     = (us*)w;    w += (size_t)512*256*2;
  us* W3b     = (us*)w;    w += (size_t)256*128*2;
  us* Wqsb    = (us*)w;    w += 32768*2;
  us* Wksb    = (us*)w;    w += 32768*2;
  us* Wqcb    = (us*)w;    w += 32768*2;
  us* Wkcb    = (us*)w;    w += 32768*2;
  us* h1b     = (us*)w;    w += (size_t)3840*512*2;
  us* h2b     = (us*)w;    w += (size_t)3840*256*2;
  float* hbp  = (float*)w; w += (size_t)3840*128*4;
  us* z1b     = (us*)w;    w += (size_t)3840*128*2;
  us* z3b     = (us*)w;    w += (size_t)3840*128*2;
  float* e2p  = (float*)w; w += (size_t)3840*128*4;
  us* Qb      = (us*)w;    w += (size_t)3840*256*2;
  us* Kb      = (us*)w;    w += (size_t)3840*256*2;
  us* VT      = (us*)w;    w += (size_t)48*256*80*2;
  us* WfcTe   = (us*)w;    w += 16384*2;
  us* WfcTd   = (us*)w;    w += 16384*2;
  us* Mb      = (us*)w;    w += 32768*2;
  us* Wvhb_s  = (us*)w;    w += 32768*2;
  us* Wvhb_c  = (us*)w;    w += 32768*2;
  us* x4g     = (us*)w;    w += (size_t)2304*10240*2;   // 47.2 MB

  // bulk conversions + weight folds
  hipLaunchKernelGGL(cvt_k, dim3(2048), dim3(256), 0, stream,
                     x, W1, W2, W3, Wq_s, Wk_s, Wq_c, Wk_c,
                     xb, W1b, W2b, W3b, Wqsb, Wksb, Wqcb, Wkcb);
  hipLaunchKernelGGL(prep_k, dim3(128, 8), dim3(128), 0, stream,
                     Wh_s, Wfc_e, Wh_c, Wfc_d, Wcs, Wv_s, Wv_c,
                     WfcTe, WfcTd, Wvhb_s, Wvhb_c, Mb);
  // MLP (all-bf16)
  hipLaunchKernelGGL(bgemm_k, dim3(8,60), dim3(256), 0, stream,
                     xb, W1b, h1b, 512, 512);
  hipLaunchKernelGGL(bgemm_k, dim3(4,60), dim3(256), 0, stream,
                     h1b, W2b, h2b, 256, 512);
  // MLP3 + fused norm -> hbp (permuted f32), z1b (bf16)
  hipLaunchKernelGGL(nmgemm_k, dim3(60), dim3(256), 0, stream,
                     h2b, W3b, hbp, z1b);
  // encoder QKV
  hipLaunchKernelGGL(qkv2_k, dim3(12,60), dim3(256), 0, stream,
                     z1b, Wqsb, Wksb, Wvhb_s, Qb, Kb, VT);
  hipLaunchKernelGGL(enc_k, dim3(48), dim3(320), 0, stream,
                     Qb, Kb, VT, hbp, WfcTe, e2p, z3b);
  // decoder QKV
  hipLaunchKernelGGL(qkv2_k, dim3(12,60), dim3(256), 0, stream,
                     z3b, Wqcb, Wkcb, Wvhb_c, Qb, Kb, VT);
  // decoder attention
  hipLaunchKernelGGL(dec8_k, dim3(48,24), dim3(640), 0, stream,
                     Qb, Kb, VT, e2p, WfcTd, x4g);
  // fused U-projection + score
  hipLaunchKernelGGL(up_k, dim3(1176), dim3(320), 0, stream,
                     x4g, Mb, Wcs2, xs, out);
}

// Round 21
// 239.825 us; speedup vs baseline: 1.0171x; 1.0171x over previous
//
#include <hip/hip_runtime.h>
#include <hip/hip_bf16.h>

// SetMatchingModel S=48,N=80,D=128,H=2,HS=128.
// FINAL (= round-19 best, 240us): encoder pair-independence + symmetric-score
// triangle + Wh/Wcs algebraic folds; dec8_k = 640-thr 2-wave-group blocks,
// 4-phase LDS ring w/ resident Wfc; up_k = fused U-projection + score.
// Round-20's front-end cleanup measured neutral-negative -> reverted.

#define SS 48
#define NI 80

typedef unsigned short us;
typedef __attribute__((ext_vector_type(8))) short s8v;   // 8 bf16
typedef __attribute__((ext_vector_type(4))) float f4v;   // 4 f32

#define MFMA(a,b,c) __builtin_amdgcn_mfma_f32_16x16x32_bf16((a),(b),(c),0,0,0)

__device__ __forceinline__ float gelu_f(float x){
  return 0.5f * x * (1.0f + erff(x * 0.7071067811865475f));
}
__device__ __forceinline__ us f2b(float f){
  __hip_bfloat16 b = __float2bfloat16(f);
  return reinterpret_cast<us&>(b);
}
__device__ __forceinline__ s8v zero8(){ s8v v = {0,0,0,0,0,0,0,0}; return v; }
__device__ __forceinline__ void gl16(const void* g, void* l){
  __builtin_amdgcn_global_load_lds(
      (const __attribute__((address_space(1))) void*)g,
      (__attribute__((address_space(3))) void*)l, 16, 0, 0);
}

// ---------------- bf16 MFMA GEMM: C = gelu(A[M,K] @ B[K,N]) -----------------
template<int ABF16, int OUTF32>
__global__ __launch_bounds__(256) void mgemm_k(const void* __restrict__ Ap,
    const float* __restrict__ B, void* __restrict__ Cp, int N, int K)
{
  __shared__ __align__(16) char lds[10240];
  char* As = lds; char* Bs = lds + 5120;
  const int t = threadIdx.x;
  const int wv = t >> 6, lm = t & 15, lh = (t >> 4) & 3;
  const int bx = blockIdx.x, by = blockIdx.y;
  const int ar = wv*16 + lm, r0 = wv*16 + lh*4;
  f4v acc[4];
#pragma unroll
  for (int ct = 0; ct < 4; ++ct) acc[ct] = {0.f,0.f,0.f,0.f};
  const int rA = t >> 2, kcA = (t & 3) << 3;
  const int kkB = t >> 3, nnB = (t & 7) << 3;
  for (int k0 = 0; k0 < K; k0 += 32) {
    __syncthreads();
    if (ABF16) {
      s8v v = *(const s8v*)((const us*)Ap + (size_t)(by*64 + rA)*K + k0 + kcA);
      *(s8v*)(As + rA*80 + kcA*2) = v;
    } else {
      const float* ap = (const float*)Ap + (size_t)(by*64 + rA)*K + k0 + kcA;
      float4 v0 = *(const float4*)ap, v1 = *(const float4*)(ap + 4);
      us tmp[8] = {f2b(v0.x),f2b(v0.y),f2b(v0.z),f2b(v0.w),
                   f2b(v1.x),f2b(v1.y),f2b(v1.z),f2b(v1.w)};
      *(s8v*)(As + rA*80 + kcA*2) = *(const s8v*)tmp;
    }
    {
      const float* bp = B + (size_t)(k0 + kkB)*N + bx*64 + nnB;
      float4 w0 = *(const float4*)bp, w1 = *(const float4*)(bp + 4);
      float w8[8] = {w0.x,w0.y,w0.z,w0.w,w1.x,w1.y,w1.z,w1.w};
#pragma unroll
      for (int q = 0; q < 8; ++q)
        *(us*)(Bs + (nnB + q)*80 + kkB*2) = f2b(w8[q]);
    }
    __syncthreads();
    s8v af = *(const s8v*)(As + ar*80 + lh*16);
#pragma unroll
    for (int ct = 0; ct < 4; ++ct) {
      s8v bf = *(const s8v*)(Bs + (ct*16 + lm)*80 + lh*16);
      acc[ct] = MFMA(af, bf, acc[ct]);
    }
  }
#pragma unroll
  for (int ct = 0; ct < 4; ++ct)
#pragma unroll
    for (int reg = 0; reg < 4; ++reg) {
      size_t r = by*64 + r0 + reg;
      int c = bx*64 + ct*16 + lm;
      float v = gelu_f(acc[ct][reg]);
      if (OUTF32) ((float*)Cp)[r*N + c] = v;
      else ((us*)Cp)[r*N + c] = f2b(v);
    }
}

// ---------------- fused QKV GEMM (K=128, N=256 each), V -> VT scatter -------
__global__ __launch_bounds__(256) void qkv_k(const us* __restrict__ A,
    const float* __restrict__ Wq, const float* __restrict__ Wk,
    const float* __restrict__ Wv, us* __restrict__ Qb, us* __restrict__ Kb,
    us* __restrict__ VT)
{
  __shared__ __align__(16) char lds[10240];
  char* As = lds; char* Bs = lds + 5120;
  const int t = threadIdx.x;
  const int wv = t >> 6, lm = t & 15, lh = (t >> 4) & 3;
  const int bx = blockIdx.x, by = blockIdx.y;
  const int sel = bx >> 2, bxx = bx & 3;
  const float* B = sel == 0 ? Wq : (sel == 1 ? Wk : Wv);
  const int ar = wv*16 + lm, r0 = wv*16 + lh*4;
  f4v acc[4];
#pragma unroll
  for (int ct = 0; ct < 4; ++ct) acc[ct] = {0.f,0.f,0.f,0.f};
  const int rA = t >> 2, kcA = (t & 3) << 3;
  const int kkB = t >> 3, nnB = (t & 7) << 3;
#pragma unroll
  for (int k0 = 0; k0 < 128; k0 += 32) {
    __syncthreads();
    {
      s8v v = *(const s8v*)(A + (size_t)(by*64 + rA)*128 + k0 + kcA);
      *(s8v*)(As + rA*80 + kcA*2) = v;
      const float* bp = B + (size_t)(k0 + kkB)*256 + bxx*64 + nnB;
      float4 w0 = *(const float4*)bp, w1 = *(const float4*)(bp + 4);
      float w8[8] = {w0.x,w0.y,w0.z,w0.w,w1.x,w1.y,w1.z,w1.w};
#pragma unroll
      for (int q = 0; q < 8; ++q)
        *(us*)(Bs + (nnB + q)*80 + kkB*2) = f2b(w8[q]);
    }
    __syncthreads();
    s8v af = *(const s8v*)(As + ar*80 + lh*16);
#pragma unroll
    for (int ct = 0; ct < 4; ++ct) {
      s8v bf = *(const s8v*)(Bs + (ct*16 + lm)*80 + lh*16);
      acc[ct] = MFMA(af, bf, acc[ct]);
    }
  }
  if (sel < 2) {
    us* O = sel ? Kb : Qb;
#pragma unroll
    for (int ct = 0; ct < 4; ++ct)
#pragma unroll
      for (int reg = 0; reg < 4; ++reg)
        O[(size_t)(by*64 + r0 + reg)*256 + bxx*64 + ct*16 + lm] = f2b(acc[ct][reg]);
  } else {
#pragma unroll
    for (int ct = 0; ct < 4; ++ct)
#pragma unroll
      for (int reg = 0; reg < 4; ++reg) {
        int r = by*64 + r0 + reg;
        int s = r / 80, m = r % 80;
        int d = bxx*64 + ct*16 + lm;
        VT[((size_t)s*256 + d)*80 + m] = f2b(acc[ct][reg]);
      }
  }
}

// ---------------- per-row item layer norm, bf16 out -------------------------
__global__ __launch_bounds__(64) void norm_k(const float* __restrict__ in,
                                             us* __restrict__ out)
{
  const int r = blockIdx.x, t = threadIdx.x;
  float v0 = in[(size_t)r*128 + t];
  float v1 = in[(size_t)r*128 + t + 64];
  float sm = v0 + v1;
#pragma unroll
  for (int off = 1; off < 64; off <<= 1) sm += __shfl_xor(sm, off, 64);
  float mean = sm * (1.0f/128.0f);
  float d0 = v0 - mean, d1 = v1 - mean;
  float vs = d0*d0 + d1*d1;
#pragma unroll
  for (int off = 1; off < 64; off <<= 1) vs += __shfl_xor(vs, off, 64);
  float inv = 1.0f / (sqrtf(vs * (1.0f/128.0f)) + 1e-3f);
  bool keep = (sm != 0.0f);
  out[(size_t)r*128 + t]      = f2b(keep ? d0*inv : 0.0f);
  out[(size_t)r*128 + t + 64] = f2b(keep ? d1*inv : 0.0f);
}

// ---------------- merged weight prep ----------------------------------------
__global__ __launch_bounds__(128) void prep_k(
    const float* __restrict__ Wh_s, const float* __restrict__ Wfc_e,
    const float* __restrict__ Wh_c, const float* __restrict__ Wfc_d,
    const float* __restrict__ Wcs,  const float* __restrict__ Wv_s,
    const float* __restrict__ Wv_c,
    us* __restrict__ WfcTe, us* __restrict__ WfcTd,
    float* __restrict__ Wvh_s, float* __restrict__ Wvh_c,
    us* __restrict__ Mb)
{
  const int x = blockIdx.x, task = blockIdx.y, tid = threadIdx.x;
  if (task == 0) {
    WfcTe[x*128 + tid] = f2b(Wfc_e[(size_t)tid*128 + x]);
  } else if (task == 1) {
    WfcTd[x*128 + tid] = f2b(Wfc_d[(size_t)tid*128 + x]);
  } else if (task < 6) {
    int h = (task - 2) & 1;
    const float* Wv = task < 4 ? Wv_s : Wv_c;
    const float* Wh = task < 4 ? Wh_s : Wh_c;
    float* Wvh = task < 4 ? Wvh_s : Wvh_c;
    float acc = 0.f;
#pragma unroll 8
    for (int d = 0; d < 128; ++d)
      acc = fmaf(Wv[(size_t)x*256 + h*128 + d], Wh[(size_t)(h*128 + d)*128 + tid], acc);
    Wvh[(size_t)x*256 + h*128 + tid] = acc;
  } else {
    int h = task - 6;
    float acc = 0.f;
#pragma unroll 8
    for (int k = 0; k < 128; ++k)
      acc = fmaf(Wcs[(size_t)x*256 + h*128 + k], Wcs[(size_t)tid*256 + h*128 + k], acc);
    Mb[(size_t)h*16384 + x*128 + tid] = f2b(acc);
  }
}

// ---------------- staged attention (drain-style; enc_k only, 48 blocks) -----
__device__ __forceinline__ void attn4e(int a, int t,
    const us* __restrict__ Qg, const us* __restrict__ Kg,
    const us* __restrict__ VTg, const float* __restrict__ baseg,
    const us* __restrict__ WfcT,
    char* __restrict__ X, char* __restrict__ Y, f4v x4[8])
{
  const int wv = t >> 6, lane = t & 63, lm = t & 15, lh = (t >> 4) & 3;
  const int ar = wv*16 + lm, r0 = wv*16 + lh*4;
  const float isq = 0.08838834764831845f;
  const int b = a;
#pragma unroll
  for (int dt = 0; dt < 8; ++dt) x4[dt] = (f4v){0.f,0.f,0.f,0.f};

#pragma unroll 1
  for (int h = 0; h < 2; ++h) {
    if (h == 1) __syncthreads();
#pragma unroll
    for (int c = 0; c < 4; ++c) {
      int chunk = wv*4 + c;
      int row = chunk*4 + (lane >> 4);
      int scb = ((lane & 15) << 4) ^ ((row & 7) << 4);
      gl16(Kg + (((size_t)(b*NI + row)) << 8) + h*128 + (scb >> 1), X + chunk*1024);
    }
    s8v qf[4];
    {
      const us* qrow = Qg + (((size_t)(a*NI + ar)) << 8) + h*128 + lh*8;
#pragma unroll
      for (int ks = 0; ks < 4; ++ks) qf[ks] = *(const s8v*)(qrow + ks*32);
    }
    __syncthreads();
    f4v sA[5];
#pragma unroll
    for (int nt = 0; nt < 5; ++nt) {
      int row = nt*16 + lm;
      f4v acc = (f4v){0.f,0.f,0.f,0.f};
#pragma unroll
      for (int ks = 0; ks < 4; ++ks) {
        s8v kf = *(const s8v*)(X + row*256 + ((ks*64 + lh*16) ^ ((row & 7) << 4)));
        acc = MFMA(qf[ks], kf, acc);
      }
      sA[nt] = acc;
    }
#pragma unroll
    for (int reg = 0; reg < 4; ++reg) {
      int r = r0 + reg;
      float sv[5];
#pragma unroll
      for (int nt = 0; nt < 5; ++nt) sv[nt] = sA[nt][reg] * isq;
      float mx = sv[0];
#pragma unroll
      for (int nt = 1; nt < 5; ++nt) mx = fmaxf(mx, sv[nt]);
#pragma unroll
      for (int off = 1; off < 16; off <<= 1) mx = fmaxf(mx, __shfl_xor(mx, off, 64));
      float e[5], sum = 0.f;
#pragma unroll
      for (int nt = 0; nt < 5; ++nt) {
        e[nt] = (sv[nt] != 0.f) ? __expf(sv[nt] - mx) : 0.f;
        sum += e[nt];
      }
#pragma unroll
      for (int off = 1; off < 16; off <<= 1) sum += __shfl_xor(sum, off, 64);
      float inv = 1.f / (sum + 1e-10f);
#pragma unroll
      for (int nt = 0; nt < 5; ++nt)
        *(us*)(Y + r*256 + ((2*(nt*16 + lm)) ^ ((r & 7) << 4))) = f2b(e[nt] * inv);
    }
    s8v pf0 = *(const s8v*)(Y + ar*256 + ((lh*16) ^ ((ar & 7) << 4)));
    s8v pf1 = *(const s8v*)(Y + ar*256 + ((64 + lh*16) ^ ((ar & 7) << 4)));
    s8v pf2 = zero8();
    if (lh < 2)
      pf2 = *(const s8v*)(Y + ar*256 + ((128 + lh*16) ^ ((ar & 7) << 4)));
    __syncthreads();
#pragma unroll
    for (int c = 0; c < 4; ++c) {
      int chunk = wv*4 + c;
      int L = chunk*1024 + lane*16;
      int rv = L / 160;
      int rem = L - rv*160;
      int cv = (rem >> 4) - (rv % 10); if (cv < 0) cv += 10;
      gl16(VTg + ((size_t)(b*256 + h*128 + rv))*80 + (cv << 3), X + chunk*1024);
    }
    __syncthreads();
#pragma unroll
    for (int dt = 0; dt < 8; ++dt) {
      int row = dt*16 + lm;
      int rm = (row % 10) << 4;
      int o0 = lh*16 + rm; if (o0 >= 160) o0 -= 160;
      x4[dt] = MFMA(pf0, *(const s8v*)(X + row*160 + o0), x4[dt]);
      int o1 = 64 + lh*16 + rm; if (o1 >= 160) o1 -= 160;
      x4[dt] = MFMA(pf1, *(const s8v*)(X + row*160 + o1), x4[dt]);
      s8v v2 = zero8();
      if (lh < 2) {
        int o2 = 128 + lh*16 + rm; if (o2 >= 160) o2 -= 160;
        v2 = *(const s8v*)(X + row*160 + o2);
      }
      x4[dt] = MFMA(pf2, v2, x4[dt]);
    }
    if (h == 1) {
#pragma unroll
      for (int reg = 0; reg < 4; ++reg) {
        int r = r0 + reg;
#pragma unroll
        for (int dt = 0; dt < 8; ++dt)
          x4[dt][reg] += baseg[(((size_t)(a*NI + r)) << 7) + dt*16 + lm];
      }
    }
  }

  __syncthreads();
  for (int chunk = wv; chunk < 16; chunk += 5) {
    int row = chunk*4 + (lane >> 4);
    int scb = ((lane & 15) << 4) ^ ((row & 7) << 4);
    gl16(WfcT + (size_t)row*128 + (scb >> 1), X + chunk*1024);
  }
#pragma unroll
  for (int reg = 0; reg < 4; ++reg) {
    int r = r0 + reg;
    float sm = 0.f;
#pragma unroll
    for (int dt = 0; dt < 8; ++dt) sm += x4[dt][reg];
#pragma unroll
    for (int off = 1; off < 16; off <<= 1) sm += __shfl_xor(sm, off, 64);
    float mean = sm * (1.0f/128.0f);
    float vs = 0.f;
#pragma unroll
    for (int dt = 0; dt < 8; ++dt) { float d = x4[dt][reg] - mean; vs = fmaf(d, d, vs); }
#pragma unroll
    for (int off = 1; off < 16; off <<= 1) vs += __shfl_xor(vs, off, 64);
    float inv = 1.f / (sqrtf(vs * (1.0f/128.0f)) + 1e-3f);
    bool keep = (sm != 0.f);
#pragma unroll
    for (int dt = 0; dt < 8; ++dt)
      *(us*)(Y + r*256 + ((2*(dt*16 + lm)) ^ ((r & 7) << 4))) = f2b(keep ? (x4[dt][reg]-mean)*inv : 0.f);
  }
  s8v zf[4];
#pragma unroll
  for (int ks = 0; ks < 4; ++ks)
    zf[ks] = *(const s8v*)(Y + ar*256 + ((ks*64 + lh*16) ^ ((ar & 7) << 4)));
  __syncthreads();
#pragma unroll
  for (int dt = 0; dt < 4; ++dt) {
    int row = dt*16 + lm;
    f4v acc = (f4v){0.f,0.f,0.f,0.f};
#pragma unroll
    for (int ks = 0; ks < 4; ++ks) {
      s8v wfr = *(const s8v*)(X + row*256 + ((ks*64 + lh*16) ^ ((row & 7) << 4)));
      acc = MFMA(zf[ks], wfr, acc);
    }
#pragma unroll
    for (int reg = 0; reg < 4; ++reg) x4[dt][reg] += gelu_f(acc[reg]);
  }
  __syncthreads();
  for (int chunk = wv; chunk < 16; chunk += 5) {
    int row = chunk*4 + (lane >> 4);
    int scb = ((lane & 15) << 4) ^ ((row & 7) << 4);
    gl16(WfcT + (size_t)(row + 64)*128 + (scb >> 1), X + chunk*1024);
  }
  __syncthreads();
#pragma unroll
  for (int dt = 4; dt < 8; ++dt) {
    int row = dt*16 + lm;
    int r2 = row - 64;
    f4v acc = (f4v){0.f,0.f,0.f,0.f};
#pragma unroll
    for (int ks = 0; ks < 4; ++ks) {
      s8v wfr = *(const s8v*)(X + r2*256 + ((ks*64 + lh*16) ^ ((row & 7) << 4)));
      acc = MFMA(zf[ks], wfr, acc);
    }
#pragma unroll
    for (int reg = 0; reg < 4; ++reg) x4[dt][reg] += gelu_f(acc[reg]);
  }
}

// ---------------- encoder kernel --------------------------------------------
__global__ __launch_bounds__(320) void enc_k(
    const us* __restrict__ Qg, const us* __restrict__ Kg,
    const us* __restrict__ VTg, const float* __restrict__ hb,
    const us* __restrict__ WfcT, float* __restrict__ e2p,
    us* __restrict__ z3b)
{
  __shared__ __align__(16) char X[20480];
  __shared__ __align__(16) char Y[20480];
  const int t = threadIdx.x;
  const int wv = t >> 6, lm = t & 15, lh = (t >> 4) & 3;
  const int r0 = wv*16 + lh*4;
  const int i = blockIdx.x;
  f4v x4[8];
  attn4e(i, t, Qg, Kg, VTg, hb, WfcT, X, Y, x4);
#pragma unroll
  for (int reg = 0; reg < 4; ++reg) {
    int r = r0 + reg;
    size_t gb = ((size_t)(i*NI + r)) << 7;
    float tmp[8]; float sm = 0.f;
#pragma unroll
    for (int dt = 0; dt < 8; ++dt) { tmp[dt] = x4[dt][reg]; sm += tmp[dt]; }
    *(float4*)(e2p + gb + lm*8)     = make_float4(tmp[0],tmp[1],tmp[2],tmp[3]);
    *(float4*)(e2p + gb + lm*8 + 4) = make_float4(tmp[4],tmp[5],tmp[6],tmp[7]);
#pragma unroll
    for (int off = 1; off < 16; off <<= 1) sm += __shfl_xor(sm, off, 64);
    float mean = sm * (1.0f/128.0f);
    float vs = 0.f;
#pragma unroll
    for (int dt = 0; dt < 8; ++dt) { float d = tmp[dt] - mean; vs = fmaf(d, d, vs); }
#pragma unroll
    for (int off = 1; off < 16; off <<= 1) vs += __shfl_xor(vs, off, 64);
    float inv = 1.f / (sqrtf(vs * (1.0f/128.0f)) + 1e-3f);
    bool keep = (sm != 0.f);
#pragma unroll
    for (int dt = 0; dt < 8; ++dt)
      z3b[gb + dt*16 + lm] = f2b(keep ? (tmp[dt]-mean)*inv : 0.f);
  }
}

// ---------------- dec8_k: 640 thr, 2 groups, resident Wfc, 4 phases ---------
__global__ __launch_bounds__(640, 2) void dec8_k(
    const us* __restrict__ Qg, const us* __restrict__ Kg,
    const us* __restrict__ VTg, const float* __restrict__ e2p,
    const us* __restrict__ WfcT, us* __restrict__ x4g)
{
  __shared__ __align__(16) char L[155648];   // W 32K + 2 x (S0 20K,S1 20K,Y 20K)
  const int t = threadIdx.x;
  const int g = (t >= 320) ? 1 : 0;
  const int tg = t - g*320;
  const int wv = tg >> 6, wb = t >> 6;
  const int lane = t & 63, lm = t & 15, lh = (t >> 4) & 3;
  const int ar = wv*16 + lm, r0 = wv*16 + lh*4;
  const float isq = 0.08838834764831845f;
  const int a = blockIdx.x, b = blockIdx.y*2 + g;
  char* W  = L;
  char* S0 = L + 32768 + g*61440;
  char* S1 = S0 + 20480;
  char* Y  = S0 + 40960;

#define STG_K(DST, H)                                                        \
  { _Pragma("unroll") for (int c_ = 0; c_ < 4; ++c_) {                       \
      int ch_ = wv*4 + c_;                                                   \
      int rw_ = ch_*4 + (lane >> 4);                                         \
      int sc_ = ((lane & 15) << 4) ^ ((rw_ & 7) << 4);                       \
      gl16(Kg + (((size_t)(b*NI + rw_)) << 8) + (H)*128 + (sc_ >> 1),        \
           (DST) + ch_*1024); } }
#define STG_VT(DST, H)                                                       \
  { _Pragma("unroll") for (int c_ = 0; c_ < 4; ++c_) {                       \
      int ch_ = wv*4 + c_;                                                   \
      int L_ = ch_*1024 + lane*16;                                           \
      int rv_ = L_ / 160;                                                    \
      int cv_ = ((L_ - rv_*160) >> 4) - (rv_ % 10); if (cv_ < 0) cv_ += 10;  \
      gl16(VTg + ((size_t)(b*256 + (H)*128 + rv_))*80 + (cv_ << 3),          \
           (DST) + ch_*1024); } }
#define QKSM(KS, H)                                                          \
  { s8v qf_[4];                                                              \
    { const us* qr_ = Qg + (((size_t)(a*NI + ar)) << 8) + (H)*128 + lh*8;    \
      _Pragma("unroll") for (int ks = 0; ks < 4; ++ks)                       \
        qf_[ks] = *(const s8v*)(qr_ + ks*32); }                              \
    f4v sA_[5];                                                              \
    _Pragma("unroll") for (int nt = 0; nt < 5; ++nt) {                       \
      int rw_ = nt*16 + lm;                                                  \
      f4v ac_ = (f4v){0.f,0.f,0.f,0.f};                                      \
      _Pragma("unroll") for (int ks = 0; ks < 4; ++ks) {                     \
        s8v kf_ = *(const s8v*)((KS) + rw_*256 +                             \
                                ((ks*64 + lh*16) ^ ((rw_ & 7) << 4)));       \
        ac_ = MFMA(qf_[ks], kf_, ac_); }                                     \
      sA_[nt] = ac_; }                                                       \
    _Pragma("unroll") for (int reg = 0; reg < 4; ++reg) {                    \
      int r_ = r0 + reg;                                                     \
      float sv_[5];                                                          \
      _Pragma("unroll") for (int nt = 0; nt < 5; ++nt)                       \
        sv_[nt] = sA_[nt][reg] * isq;                                        \
      float mx_ = sv_[0];                                                    \
      _Pragma("unroll") for (int nt = 1; nt < 5; ++nt)                       \
        mx_ = fmaxf(mx_, sv_[nt]);                                           \
      _Pragma("unroll") for (int of_ = 1; of_ < 16; of_ <<= 1)               \
        mx_ = fmaxf(mx_, __shfl_xor(mx_, of_, 64));                          \
      float e_[5], su_ = 0.f;                                                \
      _Pragma("unroll") for (int nt = 0; nt < 5; ++nt) {                     \
        e_[nt] = (sv_[nt] != 0.f) ? __expf(sv_[nt] - mx_) : 0.f;             \
        su_ += e_[nt]; }                                                     \
      _Pragma("unroll") for (int of_ = 1; of_ < 16; of_ <<= 1)               \
        su_ += __shfl_xor(su_, of_, 64);                                     \
      float iv_ = 1.f / (su_ + 1e-10f);                                      \
      _Pragma("unroll") for (int nt = 0; nt < 5; ++nt)                       \
        *(us*)(Y + r_*256 + ((2*(nt*16 + lm)) ^ ((r_ & 7) << 4))) =          \
            f2b(e_[nt] * iv_); } }
#define PV(VS)                                                               \
  { s8v pf0_ = *(const s8v*)(Y + ar*256 + ((lh*16) ^ ((ar & 7) << 4)));      \
    s8v pf1_ = *(const s8v*)(Y + ar*256 + ((64 + lh*16) ^ ((ar & 7) << 4))); \
    s8v pf2_ = zero8();                                                      \
    if (lh < 2)                                                              \
      pf2_ = *(const s8v*)(Y + ar*256 + ((128 + lh*16) ^ ((ar & 7) << 4)));  \
    _Pragma("unroll") for (int dt = 0; dt < 8; ++dt) {                       \
      int rw_ = dt*16 + lm;                                                  \
      int rm_ = (rw_ % 10) << 4;                                             \
      int o0_ = lh*16 + rm_; if (o0_ >= 160) o0_ -= 160;                     \
      x4[dt] = MFMA(pf0_, *(const s8v*)((VS) + rw_*160 + o0_), x4[dt]);      \
      int o1_ = 64 + lh*16 + rm_; if (o1_ >= 160) o1_ -= 160;                \
      x4[dt] = MFMA(pf1_, *(const s8v*)((VS) + rw_*160 + o1_), x4[dt]);      \
      s8v v2_ = zero8();                                                     \
      if (lh < 2) { int o2_ = 128 + lh*16 + rm_;                             \
        if (o2_ >= 160) o2_ -= 160;                                          \
        v2_ = *(const s8v*)((VS) + rw_*160 + o2_); }                         \
      x4[dt] = MFMA(pf2_, v2_, x4[dt]); } }

  f4v x4[8];
#pragma unroll
  for (int dt = 0; dt < 8; ++dt) x4[dt] = (f4v){0.f,0.f,0.f,0.f};

  // prologue: resident Wfc (block-cooperative) + K0
  for (int ch = wb; ch < 32; ch += 10) {
    int row = ch*4 + (lane >> 4);
    int scb = ((lane & 15) << 4) ^ ((row & 7) << 4);
    gl16(WfcT + (size_t)row*128 + (scb >> 1), W + ch*1024);
  }
  STG_K(S0, 0);
  __syncthreads();
  // P0: issue VT0 -> S1; compute QK0 + softmax
  STG_VT(S1, 0);
  QKSM(S0, 0);
  __syncthreads();
  // P1: issue K1 -> S0; compute PV0
  STG_K(S0, 1);
  PV(S1);
  __syncthreads();
  // P2: issue VT1 -> S1; compute QK1 + softmax
  STG_VT(S1, 1);
  QKSM(S0, 1);
  __syncthreads();
  // P3 (final): PV1 + residual + norm + FC (all 8, resident W) + store
  PV(S1);
#pragma unroll
  for (int reg = 0; reg < 4; ++reg) {
    const f4v* bp = (const f4v*)(e2p + (((size_t)(a*NI + r0 + reg)) << 7) + lm*8);
    f4v bb0 = bp[0], bb1 = bp[1];
#pragma unroll
    for (int dt = 0; dt < 4; ++dt) {
      x4[dt][reg]   += bb0[dt];
      x4[dt+4][reg] += bb1[dt];
    }
  }
#pragma unroll
  for (int reg = 0; reg < 4; ++reg) {
    int r = r0 + reg;
    float sm = 0.f;
#pragma unroll
    for (int dt = 0; dt < 8; ++dt) sm += x4[dt][reg];
#pragma unroll
    for (int off = 1; off < 16; off <<= 1) sm += __shfl_xor(sm, off, 64);
    float mean = sm * (1.0f/128.0f);
    float vs = 0.f;
#pragma unroll
    for (int dt = 0; dt < 8; ++dt) { float d = x4[dt][reg] - mean; vs = fmaf(d, d, vs); }
#pragma unroll
    for (int off = 1; off < 16; off <<= 1) vs += __shfl_xor(vs, off, 64);
    float inv = 1.f / (sqrtf(vs * (1.0f/128.0f)) + 1e-3f);
    bool keep = (sm != 0.f);
#pragma unroll
    for (int dt = 0; dt < 8; ++dt)
      *(us*)(Y + r*256 + ((2*(dt*16 + lm)) ^ ((r & 7) << 4))) = f2b(keep ? (x4[dt][reg]-mean)*inv : 0.f);
  }
  {
    s8v zf[4];
#pragma unroll
    for (int ks = 0; ks < 4; ++ks)
      zf[ks] = *(const s8v*)(Y + ar*256 + ((ks*64 + lh*16) ^ ((ar & 7) << 4)));
#pragma unroll
    for (int dt = 0; dt < 8; ++dt) {
      int row = dt*16 + lm;
      f4v ac = (f4v){0.f,0.f,0.f,0.f};
#pragma unroll
      for (int ks = 0; ks < 4; ++ks) {
        s8v wf = *(const s8v*)(W + row*256 + ((ks*64 + lh*16) ^ ((row & 7) << 4)));
        ac = MFMA(zf[ks], wf, ac);
      }
#pragma unroll
      for (int reg = 0; reg < 4; ++reg) x4[dt][reg] += gelu_f(ac[reg]);
    }
  }
#pragma unroll
  for (int reg = 0; reg < 4; ++reg) {
    int r = r0 + reg;
#pragma unroll
    for (int dt = 0; dt < 8; ++dt)
      *(us*)(Y + r*256 + ((2*(dt*16 + lm)) ^ ((r & 7) << 4))) = f2b(x4[dt][reg]);
  }
  {
    char* dst = (char*)(x4g + ((size_t)a*SS + b)*10240);
#pragma unroll
    for (int q = 0; q < 4; ++q) {
      int c = lane + q*64;
      int row = wv*16 + (c >> 4);
      int cb = (c & 15) << 4;
      s8v v = *(const s8v*)(Y + row*256 + (cb ^ ((row & 7) << 4)));
      *(s8v*)(dst + row*256 + cb) = v;
    }
  }
#undef STG_K
#undef STG_VT
#undef QKSM
#undef PV
}

// ---------------- up_k: fused U-projection + score per unordered pair -------
__global__ __launch_bounds__(320) void up_k(
    const us* __restrict__ x4g, const us* __restrict__ Mb,
    const float* __restrict__ Wcs2, const float* __restrict__ xsg,
    float* __restrict__ outg)
{
  __shared__ __align__(16) char As[20480];
  __shared__ __align__(16) char Bs[16384];
  __shared__ __align__(16) char Xi[20480];
  __shared__ __align__(16) char Xu[40960];
  __shared__ float red[10];
  const int t = threadIdx.x;
  const int wv = t >> 6, lane = t & 63, lm = t & 15, lh = (t >> 4) & 3;
  const int ar = wv*16 + lm, r0 = wv*16 + lh*4;
  const float isq = 0.08838834764831845f;

  int bid0 = blockIdx.x;
  int bid = (bid0 & 7) * 147 + (bid0 >> 3);
  int ii = (int)(0.5f*(97.0f - sqrtf(9409.0f - 8.0f*(float)bid)));
  if (ii > 47) ii = 47; if (ii < 0) ii = 0;
  while (ii*SS - ii*(ii-1)/2 > bid) --ii;
  while ((ii+1)*SS - (ii+1)*ii/2 <= bid) ++ii;
  const int i = ii, j = ii + (bid - (ii*SS - ii*(ii-1)/2));
  const us* Aji = x4g + ((size_t)j*SS + i)*10240;
  const us* Aij = x4g + ((size_t)i*SS + j)*10240;

#pragma unroll
  for (int c = 0; c < 4; ++c) {
    int chunk = wv*4 + c;
    int row = chunk*4 + (lane >> 4);
    int scb = ((lane & 15) << 4) ^ ((row & 7) << 4);
    gl16(Aji + (size_t)row*128 + (scb >> 1), As + chunk*1024);
    gl16(Aij + (size_t)row*128 + (scb >> 1), Xi + chunk*1024);
  }
  f4v acc[16];
#pragma unroll
  for (int ct = 0; ct < 16; ++ct) acc[ct] = (f4v){0.f,0.f,0.f,0.f};
#pragma unroll 1
  for (int k0 = 0; k0 < 128; k0 += 32) {
    if (k0) __syncthreads();
    for (int c = wv; c < 16; c += 5) {
      int row = c*16 + (lane >> 2);
      int colb = (lane & 3) << 4;
      int scb = colb ^ ((row & 3) << 4);
      gl16(Mb + (size_t)row*128 + k0 + (scb >> 1), Bs + c*1024);
    }
    __syncthreads();
    int ks = k0 >> 5;
    s8v af = *(const s8v*)(As + ar*256 + ((ks*64 + lh*16) ^ ((ar & 7) << 4)));
#pragma unroll
    for (int ct = 0; ct < 16; ++ct) {
      int row = ct*16 + lm;
      s8v bf = *(const s8v*)(Bs + row*64 + ((lh*16) ^ ((row & 3) << 4)));
      acc[ct] = MFMA(af, bf, acc[ct]);
    }
  }
#pragma unroll
  for (int ct = 0; ct < 16; ++ct) {
    int h = ct >> 3;
    int cl = (ct & 7)*16 + lm;
#pragma unroll
    for (int reg = 0; reg < 4; ++reg) {
      int row = r0 + reg;
      *(us*)(Xu + h*20480 + row*256 + ((2*cl) ^ ((row & 7) << 4))) = f2b(acc[ct][reg]);
    }
  }
  __syncthreads();
  s8v xf[4];
#pragma unroll
  for (int ks = 0; ks < 4; ++ks)
    xf[ks] = *(const s8v*)(Xi + ar*256 + ((ks*64 + lh*16) ^ ((ar & 7) << 4)));
  float sc[2];
#pragma unroll 1
  for (int h = 0; h < 2; ++h) {
    const char* Xh = Xu + h*20480;
    float loc = 0.f;
#pragma unroll
    for (int nt = 0; nt < 5; ++nt) {
      int brow = nt*16 + lm;
      f4v ac = (f4v){0.f,0.f,0.f,0.f};
#pragma unroll
      for (int ks = 0; ks < 4; ++ks) {
        s8v bf = *(const s8v*)(Xh + brow*256 + ((ks*64 + lh*16) ^ ((brow & 7) << 4)));
        ac = MFMA(xf[ks], bf, ac);
      }
#pragma unroll
      for (int reg = 0; reg < 4; ++reg) loc += fmaxf(ac[reg]*isq, 0.f);
    }
    sc[h] = loc;
  }
#pragma unroll
  for (int off = 1; off < 64; off <<= 1) {
    sc[0] += __shfl_xor(sc[0], off, 64);
    sc[1] += __shfl_xor(sc[1], off, 64);
  }
  if ((t & 63) == 0) { red[wv] = sc[0]; red[wv + 5] = sc[1]; }
  __syncthreads();
  if (t == 0) {
    float s0 = red[0]+red[1]+red[2]+red[3]+red[4];
    float s1 = red[5]+red[6]+red[7]+red[8]+red[9];
    float val = (s0*Wcs2[0] + s1*Wcs2[1]) / (xsg[i]*xsg[j]);
    outg[i*SS + j] = val;
    outg[j*SS + i] = val;
  }
}

extern "C" void kernel_launch(void* const* d_in, const int* in_sizes, int n_in,
                              void* d_out, int out_size, void* d_ws, size_t ws_size,
                              hipStream_t stream)
{
  (void)in_sizes; (void)n_in; (void)out_size; (void)ws_size;
  const float* x     = (const float*)d_in[0];
  const float* xs    = (const float*)d_in[1];
  const float* W1    = (const float*)d_in[2];
  const float* W2    = (const float*)d_in[3];
  const float* W3    = (const float*)d_in[4];
  const float* Wq_s  = (const float*)d_in[5];
  const float* Wk_s  = (const float*)d_in[6];
  const float* Wv_s  = (const float*)d_in[7];
  const float* Wh_s  = (const float*)d_in[8];
  const float* Wfc_e = (const float*)d_in[9];
  const float* Wq_c  = (const float*)d_in[10];
  const float* Wk_c  = (const float*)d_in[11];
  const float* Wv_c  = (const float*)d_in[12];
  const float* Wh_c  = (const float*)d_in[13];
  const float* Wfc_d = (const float*)d_in[14];
  const float* Wcs   = (const float*)d_in[15];
  const float* Wcs2  = (const float*)d_in[16];
  float* out = (float*)d_out;

  char* w = (char*)d_ws;
  us* h1b     = (us*)w;    w += (size_t)3840*512*2;
  us* h2b     = (us*)w;    w += (size_t)3840*256*2;
  float* hb   = (float*)w; w += (size_t)3840*128*4;
  us* zb16    = (us*)w;    w += (size_t)3840*128*2;
  us* z3b     = (us*)w;    w += (size_t)3840*128*2;
  float* e2p  = (float*)w; w += (size_t)3840*128*4;
  us* Qb      = (us*)w;    w += (size_t)3840*256*2;
  us* Kb      = (us*)w;    w += (size_t)3840*256*2;
  us* VT      = (us*)w;    w += (size_t)48*256*80*2;
  us* WfcTe   = (us*)w;    w += 16384*2;
  us* WfcTd   = (us*)w;    w += 16384*2;
  us* Mb      = (us*)w;    w += 32768*2;
  float* Wvh_s = (float*)w; w += 32768*4;
  float* Wvh_c = (float*)w; w += 32768*4;
  us* x4g     = (us*)w;    w += (size_t)2304*10240*2;   // 47.2 MB

  hipLaunchKernelGGL(prep_k, dim3(128, 8), dim3(128), 0, stream,
                     Wh_s, Wfc_e, Wh_c, Wfc_d, Wcs, Wv_s, Wv_c,
                     WfcTe, WfcTd, Wvh_s, Wvh_c, Mb);
  // MLP
  hipLaunchKernelGGL((mgemm_k<0,0>), dim3(8,60), dim3(256), 0, stream,
                     (const void*)x, W1, (void*)h1b, 512, 512);
  hipLaunchKernelGGL((mgemm_k<1,0>), dim3(4,60), dim3(256), 0, stream,
                     (const void*)h1b, W2, (void*)h2b, 256, 512);
  hipLaunchKernelGGL((mgemm_k<1,1>), dim3(2,60), dim3(256), 0, stream,
                     (const void*)h2b, W3, (void*)hb, 128, 256);
  hipLaunchKernelGGL(norm_k, dim3(3840), dim3(64), 0, stream, hb, zb16);
  // encoder QKV (V folded with Wh)
  hipLaunchKernelGGL(qkv_k, dim3(12,60), dim3(256), 0, stream,
                     zb16, Wq_s, Wk_s, Wvh_s, Qb, Kb, VT);
  hipLaunchKernelGGL(enc_k, dim3(48), dim3(320), 0, stream,
                     Qb, Kb, VT, hb, WfcTe, e2p, z3b);
  // decoder QKV
  hipLaunchKernelGGL(qkv_k, dim3(12,60), dim3(256), 0, stream,
                     z3b, Wq_c, Wk_c, Wvh_c, Qb, Kb, VT);
  // decoder attention: 640 thr, 2 groups, resident Wfc, 4 phases
  hipLaunchKernelGGL(dec8_k, dim3(48,24), dim3(640), 0, stream,
                     Qb, Kb, VT, e2p, WfcTd, x4g);
  // fused U-projection + score, 1176 blocks
  hipLaunchKernelGGL(up_k, dim3(1176), dim3(320), 0, stream,
                     x4g, Mb, Wcs2, xs, out);
}